// Round 1
// 208.071 us; speedup vs baseline: 1.0101x; 1.0101x over previous
//
#include <hip/hip_runtime.h>
#include <hip/hip_fp16.h>
#include <cstdint>

#define SEQ 4096
#define DIM 1024

typedef _Float16 f16x8 __attribute__((ext_vector_type(8)));
typedef float f32x16 __attribute__((ext_vector_type(16)));
typedef __attribute__((address_space(1))) void as1_void;
typedef __attribute__((address_space(3))) void as3_void;

__device__ __forceinline__ ushort f2h(float f) {
  _Float16 h = (_Float16)f;
  return __builtin_bit_cast(ushort, h);
}

// ---------------- fused conversions: z<3 -> W transpose+cvt, z==3 -> X cvt ----------------
__global__ void convert_all_kernel(const float* __restrict__ X, const float* __restrict__ Wk,
                                   const float* __restrict__ Wv, const float* __restrict__ Wq,
                                   ushort* __restrict__ Xh, ushort* __restrict__ Wt) {
  const int z = blockIdx.z;
  const int tx = threadIdx.x, ty = threadIdx.y;  // (32,8)
  if (z == 3) {
    const int bid = blockIdx.y * 32 + blockIdx.x;
    const int t = ty * 32 + tx;
#pragma unroll
    for (int k = 0; k < 4; k++) {
      int i = bid * 1024 + k * 256 + t;
      float4 v = reinterpret_cast<const float4*>(X)[i];
      ushort4 o = { f2h(v.x), f2h(v.y), f2h(v.z), f2h(v.w) };
      reinterpret_cast<ushort4*>(Xh)[i] = o;
    }
    return;
  }
  __shared__ float tile[32][33];
  const float* W = (z == 0) ? Wk : (z == 1) ? Wv : Wq;
  int n0 = blockIdx.x * 32, k0 = blockIdx.y * 32;
#pragma unroll
  for (int r = 0; r < 4; r++) {
    int k = ty + r * 8;
    tile[k][tx] = W[(size_t)(k0 + k) * DIM + n0 + tx];
  }
  __syncthreads();
  ushort* out = Wt + (size_t)z * DIM * DIM;
#pragma unroll
  for (int r = 0; r < 4; r++) {
    int n = ty + r * 8;
    out[(size_t)(n0 + n) * DIM + k0 + tx] = f2h(tile[tx][n]);
  }
}

// ---------------- 256x256 deep-pipelined GEMM tile: 8 waves, 128x64/wave ----------------
// C[m,n] = sum_k A[m,k]*B[n,k]  (both operands K-contiguous), fp16 out.
// Double-buffered K-tiles (BK=64, 128 KiB LDS), 4 k-step phases per tile:
//   {ds_read frags | prefetch-issue | s_barrier | setprio(1) 8xMFMA setprio(0) | s_barrier}
// Raw s_barriers are hazard-free (buffer read-only within a tile); the single
// vmcnt(0) drain per tile is the __syncthreads() at the boundary, ~3 phases after
// the prefetch issue (T3+T4). XOR chunk swizzle key(r) = (r&7)^((r>>3)&3), 0 conflicts.
__device__ __forceinline__ void gemm_tile256(const ushort* __restrict__ A,
                                             const ushort* __restrict__ B,
                                             ushort* __restrict__ C,
                                             int N, int K, int m0, int n0,
                                             int kt0, int ktend) {
  constexpr int BK = 64;
  __shared__ __align__(16) ushort As[2][256 * BK];  // 2 x 32 KB
  __shared__ __align__(16) ushort Bs[2][256 * BK];  // 2 x 32 KB
  const int tid = threadIdx.x;                       // [0,512)
  const int wave = tid >> 6, lane = tid & 63;
  const int l31 = lane & 31, khalf = lane >> 5;
  const int wm = (wave & 1) * 128, wn = (wave >> 1) * 64;

  const int srow = tid >> 3;                         // [0,64)
  const int skey = ((srow & 7) ^ ((srow >> 3) & 3));
  const int sce = (((tid & 7) ^ skey) * 8);
  const int rk = (l31 & 7) ^ ((l31 >> 3) & 3);

  f32x16 acc[4][2];
#pragma unroll
  for (int i = 0; i < 4; i++)
#pragma unroll
    for (int j = 0; j < 2; j++)
#pragma unroll
      for (int r = 0; r < 16; r++) acc[i][j][r] = 0.f;

  const ushort* Abase = A + (size_t)(m0 + srow) * K + sce;
  const ushort* Bbase = B + (size_t)(n0 + srow) * K + sce;
  const int ldsbase = wave * 512;                    // ushort offset in buffer

  // prologue: stage tile 0 into buf 0 (rows srow + q*64, 1KB/wave-load)
#pragma unroll
  for (int q = 0; q < 4; q++)
    __builtin_amdgcn_global_load_lds((const as1_void*)(Abase + (size_t)q * 64 * K + kt0),
                                     (as3_void*)&As[0][ldsbase + q * 4096], 16, 0, 0);
#pragma unroll
  for (int q = 0; q < 4; q++)
    __builtin_amdgcn_global_load_lds((const as1_void*)(Bbase + (size_t)q * 64 * K + kt0),
                                     (as3_void*)&Bs[0][ldsbase + q * 4096], 16, 0, 0);
  __syncthreads();

  const int ntiles = (ktend - kt0) >> 6;             // 16 everywhere in this problem
  for (int tt = 0; tt < ntiles; ++tt) {
    const int cur = tt & 1;
    const int kt = kt0 + tt * BK;
    const bool pf = (tt + 1 < ntiles);
    const ushort* As_c = As[cur];
    const ushort* Bs_c = Bs[cur];
#pragma unroll
    for (int ks = 0; ks < 4; ks++) {
      f16x8 af[4], bf2[2];
      const int co = (((ks * 2 + khalf) ^ rk) * 8);
#pragma unroll
      for (int i = 0; i < 4; i++)
        af[i] = *reinterpret_cast<const f16x8*>(&As_c[(wm + i * 32 + l31) * BK + co]);
#pragma unroll
      for (int j = 0; j < 2; j++)
        bf2[j] = *reinterpret_cast<const f16x8*>(&Bs_c[(wn + j * 32 + l31) * BK + co]);
      if (pf && ks == 0) {
#pragma unroll
        for (int q = 0; q < 4; q++)
          __builtin_amdgcn_global_load_lds(
              (const as1_void*)(Abase + (size_t)q * 64 * K + kt + BK),
              (as3_void*)&As[cur ^ 1][ldsbase + q * 4096], 16, 0, 0);
      }
      if (pf && ks == 1) {
#pragma unroll
        for (int q = 0; q < 4; q++)
          __builtin_amdgcn_global_load_lds(
              (const as1_void*)(Bbase + (size_t)q * 64 * K + kt + BK),
              (as3_void*)&Bs[cur ^ 1][ldsbase + q * 4096], 16, 0, 0);
      }
      __builtin_amdgcn_s_barrier();
      __builtin_amdgcn_s_setprio(1);
#pragma unroll
      for (int i = 0; i < 4; i++)
#pragma unroll
        for (int j = 0; j < 2; j++)
          acc[i][j] = __builtin_amdgcn_mfma_f32_32x32x16_f16(af[i], bf2[j], acc[i][j], 0, 0, 0);
      __builtin_amdgcn_s_setprio(0);
      if (ks < 3) __builtin_amdgcn_s_barrier();
    }
    __syncthreads();  // tile boundary: the single vmcnt(0) drain + buffer handoff
  }

  // epilogue: 32x32 C/D layout col=lane&31, row=(reg&3)+8*(reg>>2)+4*(lane>>5)  [m74/m101]
#pragma unroll
  for (int i = 0; i < 4; i++)
#pragma unroll
    for (int j = 0; j < 2; j++)
#pragma unroll
      for (int r = 0; r < 16; r++) {
        int row = m0 + wm + i * 32 + (r & 3) + 8 * (r >> 2) + 4 * khalf;
        int col = n0 + wn + j * 32 + l31;
        C[(size_t)row * N + col] = f2h(acc[i][j][r]);
      }
}

// ---------------- fused K/Q/V^T projections (256 blocks of 256^2) ----------------
__global__ __launch_bounds__(512, 2) void proj256_kernel(const ushort* __restrict__ Xh,
                                                         const ushort* __restrict__ Wt,
                                                         ushort* __restrict__ Kh,
                                                         ushort* __restrict__ Qh,
                                                         ushort* __restrict__ Vt) {
  const int b = blockIdx.x;  // [0,256)
  const ushort* A;
  const ushort* B;
  ushort* Cp;
  int N, m0, n0;
  if (b < 128) {
    const int z = b >> 6, q = b & 63;           // K-proj, Q-proj: 16x4 tiles each
    A = Xh;
    B = Wt + (size_t)(z ? 2 : 0) * DIM * DIM;
    Cp = z ? Qh : Kh;
    N = DIM;
    m0 = (q >> 2) * 256;
    n0 = (q & 3) * 256;
  } else {
    const int q = b - 128;                       // V^T: M=1024 x N=4096, 4x16 tiles
    A = Wt + (size_t)DIM * DIM;
    B = Xh;
    Cp = Vt;
    N = SEQ;
    m0 = (q >> 4) * 256;
    n0 = (q & 15) * 256;
  }
  gemm_tile256(A, B, Cp, N, DIM, m0, n0, 0, DIM);
}

// ---------------- S = K @ Q^T (fp16), 256x256 tiles, XCD-swizzled ----------------
__global__ __launch_bounds__(512, 2) void score256_kernel(const ushort* __restrict__ Kh,
                                                          const ushort* __restrict__ Qh,
                                                          ushort* __restrict__ S) {
  const int f = blockIdx.x;            // [0,256)
  const int t = (f & 7) * 32 + (f >> 3);  // XCD-contiguous (256 % 8 == 0, bijective)
  gemm_tile256(Kh, Qh, S, SEQ, DIM, (t >> 4) * 256, (t & 15) * 256, 0, DIM);
}

// ---------------- O partials: split-K=4, 256x256 tiles, fp16 ----------------
__global__ __launch_bounds__(512, 2) void out256_kernel(const ushort* __restrict__ P,
                                                        const ushort* __restrict__ Vt,
                                                        ushort* __restrict__ Part) {
  const int f = blockIdx.x;            // [0,256)
  const int z = f >> 6;                // split slice
  const int q = f & 63;
  const int t = (q & 7) * 8 + (q >> 3);   // XCD swizzle within slice
  ushort* Cp = Part + (size_t)z * SEQ * DIM;
  gemm_tile256(P, Vt, Cp, DIM, SEQ, (t >> 2) * 256, (t & 3) * 256,
               z * (SEQ / 4), (z + 1) * (SEQ / 4));
}

__global__ void reduce4_kernel(const ushort* __restrict__ Part, float* __restrict__ out, int n8) {
  int i = blockIdx.x * blockDim.x + threadIdx.x;
  if (i >= n8) return;
  const f16x8* p0 = reinterpret_cast<const f16x8*>(Part);
  const f16x8* p1 = p0 + n8;
  const f16x8* p2 = p1 + n8;
  const f16x8* p3 = p2 + n8;
  f16x8 a = p0[i], b = p1[i], c = p2[i], d = p3[i];
  float4 lo, hi;
  lo.x = (float)a[0] + (float)b[0] + (float)c[0] + (float)d[0];
  lo.y = (float)a[1] + (float)b[1] + (float)c[1] + (float)d[1];
  lo.z = (float)a[2] + (float)b[2] + (float)c[2] + (float)d[2];
  lo.w = (float)a[3] + (float)b[3] + (float)c[3] + (float)d[3];
  hi.x = (float)a[4] + (float)b[4] + (float)c[4] + (float)d[4];
  hi.y = (float)a[5] + (float)b[5] + (float)c[5] + (float)d[5];
  hi.z = (float)a[6] + (float)b[6] + (float)c[6] + (float)d[6];
  hi.w = (float)a[7] + (float)b[7] + (float)c[7] + (float)d[7];
  reinterpret_cast<float4*>(out)[i * 2] = lo;
  reinterpret_cast<float4*>(out)[i * 2 + 1] = hi;
}

// ---------------- row softmax: one wave per row ----------------
__global__ __launch_bounds__(256) void softmax_kernel(const ushort* __restrict__ S,
                                                      ushort* __restrict__ P) {
  const int wave = threadIdx.x >> 6, lane = threadIdx.x & 63;
  const int row = blockIdx.x * 4 + wave;
  const ushort* s = S + (size_t)row * SEQ;
  float v[64];
#pragma unroll
  for (int i = 0; i < 8; i++) {
    f16x8 h = reinterpret_cast<const f16x8*>(s)[i * 64 + lane];
#pragma unroll
    for (int j = 0; j < 8; j++) v[i * 8 + j] = (float)h[j];
  }
  float m = v[0];
#pragma unroll
  for (int j = 1; j < 64; j++) m = fmaxf(m, v[j]);
#pragma unroll
  for (int o = 32; o > 0; o >>= 1) m = fmaxf(m, __shfl_xor(m, o, 64));
  float sum = 0.f;
#pragma unroll
  for (int j = 0; j < 64; j++) {
    v[j] = __expf(v[j] - m);
    sum += v[j];
  }
#pragma unroll
  for (int o = 32; o > 0; o >>= 1) sum += __shfl_xor(sum, o, 64);
  float inv = 1.0f / sum;
  ushort* p = P + (size_t)row * SEQ;
#pragma unroll
  for (int i = 0; i < 8; i++) {
    f16x8 h;
#pragma unroll
    for (int j = 0; j < 8; j++) h[j] = (_Float16)(v[i * 8 + j] * inv);
    reinterpret_cast<f16x8*>(p)[i * 64 + lane] = h;
  }
}

extern "C" void kernel_launch(void* const* d_in, const int* in_sizes, int n_in,
                              void* d_out, int out_size, void* d_ws, size_t ws_size,
                              hipStream_t stream) {
  const float* X = (const float*)d_in[0];
  const float* Wk = (const float*)d_in[1];
  const float* Wv = (const float*)d_in[2];
  const float* Wq = (const float*)d_in[3];

  char* ws = (char*)d_ws;
  size_t off = 0;
  ushort* Xh = (ushort*)(ws + off); off += (size_t)SEQ * DIM * 2;      // 8 MB
  ushort* Wt = (ushort*)(ws + off); off += (size_t)3 * DIM * DIM * 2;  // 6 MB
  ushort* Kh = (ushort*)(ws + off); off += (size_t)SEQ * DIM * 2;      // 8 MB
  ushort* Qh = (ushort*)(ws + off); off += (size_t)SEQ * DIM * 2;      // 8 MB
  ushort* Vt = (ushort*)(ws + off); off += (size_t)SEQ * DIM * 2;      // 8 MB
  ushort* S = (ushort*)(ws + off);  off += (size_t)SEQ * SEQ * 2;      // 32 MB (reused as partials)
  ushort* P = (ushort*)(ws + off);  off += (size_t)SEQ * SEQ * 2;      // 32 MB

  ushort* Part = S;  // 4 x [SEQ,DIM] fp16 partials alias S; S dead after softmax

  convert_all_kernel<<<dim3(32, 32, 4), dim3(32, 8), 0, stream>>>(X, Wk, Wv, Wq, Xh, Wt);
  proj256_kernel<<<256, 512, 0, stream>>>(Xh, Wt, Kh, Qh, Vt);
  score256_kernel<<<256, 512, 0, stream>>>(Kh, Qh, S);
  softmax_kernel<<<1024, 256, 0, stream>>>(S, P);
  out256_kernel<<<256, 512, 0, stream>>>(P, Vt, Part);
  reduce4_kernel<<<SEQ * DIM / 8 / 256, 256, 0, stream>>>(Part, (float*)d_out, SEQ * DIM / 8);
}